// Round 1
// baseline (35.748 us; speedup 1.0000x reference)
//
#include <hip/hip_runtime.h>

#define FT 1.0f

__device__ __forceinline__ int seqv_at(const int* pad, int S, int tl, int j) {
  return (j < S) ? min(pad[j], tl) : tl;
}

__device__ __forceinline__ int lower_b(const int* pad, int S, int tl, int v) {
  int lo = 0, hi = S + 1;
  while (lo < hi) { int mid = (lo + hi) >> 1; if (seqv_at(pad, S, tl, mid) >= v) hi = mid; else lo = mid + 1; }
  return lo;
}
__device__ __forceinline__ int upper_b(const int* pad, int S, int tl, int v) {
  int lo = 0, hi = S + 1;
  while (lo < hi) { int mid = (lo + hi) >> 1; if (seqv_at(pad, S, tl, mid) > v) hi = mid; else lo = mid + 1; }
  return lo;
}

// One block per batch row. Replicates jax-CPU numerics bit-exactly:
//  - w_sum: 16-lane strided accumulators + shuffle-halving tree (XLA:CPU vectorized reduce hypothesis)
//  - cumsum: jax lax.associative_scan recursive decomposition (up-sweep pair sums, down-sweep interleave)
__global__ __launch_bounds__(1024) void cif_row_kernel(
    const float* __restrict__ iw, const unsigned char* __restrict__ mask,
    const int* __restrict__ tlen,
    float* __restrict__ o_wsum, float* __restrict__ o_rw, float* __restrict__ o_lw,
    float* __restrict__ o_delay, float* __restrict__ o_dur,
    int* __restrict__ a_ws, int S, int T)
{
  extern __shared__ float smem[];
  float* w     = smem;           // S floats (raw clipped w, later scaled w)
  float* lv    = smem + S;       // 2*S floats: scan levels; lv[0..S) ends as csum
  float* rwArr = smem + 2 * S;   // S floats, reuses upper scan levels after scan done
  int*   pad   = (int*)(smem + 3 * S); // S ints: round(csum)
  float* red   = smem + 4 * S;   // 64 floats
  int*   aa    = (int*)(smem + 4 * S + 64); // T+1 ints: firing frame per bin
  __shared__ int s_alen, s_m;

  const int b = blockIdx.x, tid = threadIdx.x, nt = blockDim.x;
  const float* iwr = iw + (size_t)b * S;
  const unsigned char* mr = mask + (size_t)b * S;
  const int tl = tlen[b];

  if (tid == 0) { s_alen = 0; s_m = 0; }
  __syncthreads();

  // 1. clip + mask, audio_len
  int myal = 0;
  for (int s = tid; s < S; s += nt) {
    float v = iwr[s];
    v = fminf(fmaxf(v, 0.0f), 1.0f);
    if (mr[s]) v = 0.0f; else myal++;
    w[s] = v;
  }
  atomicAdd(&s_alen, myal);
  __syncthreads();

  // 2. w_sum — hypothesis: 16 strided lanes, then halving tree
  if (tid < 16) {
    float acc = 0.0f;
    for (int i = tid; i < S; i += 16) acc += w[i];
    red[tid] = acc;
  }
  __syncthreads();
  for (int h = 8; h >= 1; h >>= 1) {
    if (tid < h) red[tid] = red[tid] + red[tid + h];
    __syncthreads();
  }
  const float wsum = red[0];
  if (tid == 0) o_wsum[b] = wsum;

  // 3. scale, seed scan level 0, init firing table
  const float desired = FT * (float)tl + 1e-4f;
  const float scale = desired / wsum;
  for (int s = tid; s < S; s += nt) { float sv = w[s] * scale; w[s] = sv; lv[s] = sv; }
  for (int i = tid; i <= T; i += nt) aa[i] = (i == 0) ? -1 : S;
  __syncthreads();

  // 4. up-sweep: level k (size S>>k) at offset 2S - 2*(S>>k)
  {
    int offp = 0, off = S, sz = S >> 1;
    while (sz >= 1) {
      for (int i = tid; i < sz; i += nt)
        lv[off + i] = lv[offp + 2 * i] + lv[offp + 2 * i + 1];
      __syncthreads();
      offp = off; off += sz; sz >>= 1;
    }
  }
  // 5. down-sweep (in-place L_k -> S_k), exact jax associative_scan order
  {
    int K = 0; while ((1 << K) < S) K++;
    for (int k = K - 1; k >= 0; --k) {
      int szk = S >> k;
      int ok  = 2 * S - 2 * szk;
      int ok1 = 2 * S - szk;
      for (int j = tid; j < szk; j += nt) {
        if (j == 0) continue;
        if (j & 1) lv[ok + j] = lv[ok1 + (j >> 1)];
        else       lv[ok + j] = lv[ok1 + (j >> 1) - 1] + lv[ok + j];
      }
      __syncthreads();
    }
  }

  // 6. per-frame quantities (lv[0..S) = csum)
  for (int s = tid; s < S; s += nt) {
    float c = lv[s];
    int ri = (int)floorf(c / FT); ri = min(max(ri, 0), T);
    int li = 0;
    if (s > 0) { int rp = (int)floorf(lv[s - 1] / FT); li = min(max(rp, 0), T); }
    int n = ri - li;
    int ex = max(n - 1, 0);
    float rw = (n > 0) ? (c - (float)ri * FT) : 0.0f;
    float lwv = (w[s] - rw) - (float)ex * FT;
    o_rw[(size_t)b * S + s] = rw;
    o_lw[(size_t)b * S + s] = lwv;
    rwArr[s] = rw;
    pad[s] = (int)rintf(c);
    if (n > 0) aa[ri] = s;  // unique per bin (n_fir <= 1)
  }
  __syncthreads();

  // 7. m = number of adjacent changes in capped seq
  {
    int my = 0;
    for (int j = tid; j < S; j += nt)
      my += (seqv_at(pad, S, tl, j) != seqv_at(pad, S, tl, j + 1));
    atomicAdd(&s_m, my);
  }
  __syncthreads();
  const int m = s_m;
  const int alen = s_alen;
  const int seq0 = seqv_at(pad, S, tl, 0);
  const int L = (m >= tl) ? m : m + 1;

  // 8. delay per bin: right contribution first, then ascending lefts (matches ref scatter order)
  for (int t = tid; t < T; t += nt) {
    int start = aa[t], end = aa[t + 1];
    int s0 = (start < 0) ? 0 : start;
    int s1 = min(end, S - 1);
    float d = 0.0f;
    for (int s = s0; s <= s1; ++s) {
      float cf = (s == start) ? rwArr[s] : (w[s] - rwArr[s]);
      d = d + (cf * (float)(s + 1)) / FT;
    }
    o_delay[(size_t)b * T + t] = d;
  }

  // 9. dur per bin via binary search on monotone pad (run r <-> value seq0+r, +1 steps)
  for (int t = tid; t < T; t += nt) {
    int dv = 0;
    if (t < m) {
      int v = seq0 + t;
      dv = upper_b(pad, S, tl, v) - lower_b(pad, S, tl, v);
    }
    if (t == L - 1) dv += alen - lower_b(pad, S, tl, tl);
    o_dur[(size_t)b * T + t] = (float)dv;
  }
}

// Gather: bin t <- right_w[a_t]*in[a_t] + sum_{s in (a_t, a_{t+1}]} left_w[s]*in[s]
__global__ void cif_gather_kernel(const float* __restrict__ in,
    const float* __restrict__ rw, const float* __restrict__ lw,
    const int* __restrict__ a_ws, float* __restrict__ out,
    int S, int T, int C)
{
  const int t = blockIdx.x, b = blockIdx.y;
  const int* ab = a_ws + (size_t)b * (T + 1);
  const int start = ab[t];
  const int end = ab[t + 1];
  const int s0 = (start < 0) ? 0 : start;
  const int s1 = min(end, S - 1);
  const size_t bS = (size_t)b * S;
  const int c4 = threadIdx.x * 4;
  float4 acc = make_float4(0.f, 0.f, 0.f, 0.f);
  for (int s = s0; s <= s1; ++s) {
    const float coeff = (s == start) ? rw[bS + s] : lw[bS + s];
    const float4 v = *reinterpret_cast<const float4*>(in + (bS + s) * (size_t)C + c4);
    acc.x += coeff * v.x; acc.y += coeff * v.y;
    acc.z += coeff * v.z; acc.w += coeff * v.w;
  }
  *reinterpret_cast<float4*>(out + ((size_t)b * T + t) * (size_t)C + c4) = acc;
}

extern "C" void kernel_launch(void* const* d_in, const int* in_sizes, int n_in,
                              void* d_out, int out_size, void* d_ws, size_t ws_size,
                              hipStream_t stream)
{
  const float* inp = (const float*)d_in[0];
  const float* iw  = (const float*)d_in[1];
  const unsigned char* mask = (const unsigned char*)d_in[2]; // all-false; byte-read safe for bool or int32 encodings
  const int* tl = (const int*)d_in[3];
  const int B = in_sizes[3];
  const int S = in_sizes[1] / B;
  const int C = in_sizes[0] / in_sizes[1];
  const long long T = ((long long)out_size - B - 2LL * B * S) / ((long long)B * C + 2LL * B);

  float* o = (float*)d_out;
  float* o_out   = o;
  float* o_delay = o_out + (size_t)B * T * C;
  float* o_dur   = o_delay + (size_t)B * T;
  float* o_wsum  = o_dur + (size_t)B * T;
  float* o_rw    = o_wsum + B;
  float* o_lw    = o_rw + (size_t)B * S;
  int* a_ws = (int*)d_ws;  // B*(T+1) ints

  size_t smem = (size_t)(4 * S + 64) * sizeof(float) + (size_t)(T + 1) * sizeof(int);
  hipLaunchKernelGGL(cif_row_kernel, dim3(B), dim3(1024), smem, stream,
                     iw, mask, tl, o_wsum, o_rw, o_lw, o_delay, o_dur, a_ws, S, (int)T);
  dim3 g2((unsigned)T, (unsigned)B);
  hipLaunchKernelGGL(cif_gather_kernel, g2, dim3(C / 4), 0, stream,
                     inp, o_rw, o_lw, a_ws, o_out, S, (int)T, C);
}

// Round 2
// 32.710 us; speedup vs baseline: 1.0929x; 1.0929x over previous
//
#include <hip/hip_runtime.h>

#define FT 1.0f

__device__ __forceinline__ int seqv_at(const int* pad, int S, int tl, int j) {
  return (j < S) ? min(pad[j], tl) : tl;
}

__device__ __forceinline__ int lower_b(const int* pad, int S, int tl, int v) {
  int lo = 0, hi = S + 1;
  while (lo < hi) { int mid = (lo + hi) >> 1; if (seqv_at(pad, S, tl, mid) >= v) hi = mid; else lo = mid + 1; }
  return lo;
}
__device__ __forceinline__ int upper_b(const int* pad, int S, int tl, int v) {
  int lo = 0, hi = S + 1;
  while (lo < hi) { int mid = (lo + hi) >> 1; if (seqv_at(pad, S, tl, mid) > v) hi = mid; else lo = mid + 1; }
  return lo;
}

// One block per batch row. Bit-exact vs jax-CPU (verified round 1):
//  - w_sum: 16 strided lanes + halving tree (XLA:CPU vectorized reduce)
//  - cumsum: lax.associative_scan recursive decomposition
// Round 2: levels with <=64 active lanes run in wave 0 only (per-wave in-order
// LDS + wave_barrier to pin compiler ordering) -- same adds, same order, fewer
// s_barrier. Block size 512.
__global__ __launch_bounds__(512) void cif_row_kernel(
    const float* __restrict__ iw, const unsigned char* __restrict__ mask,
    const int* __restrict__ tlen,
    float* __restrict__ o_wsum, float* __restrict__ o_rw, float* __restrict__ o_lw,
    float* __restrict__ o_delay, float* __restrict__ o_dur,
    int* __restrict__ a_ws, int S, int T)
{
  extern __shared__ float smem[];
  float* w     = smem;           // S floats (clipped, later scaled w)
  float* lv    = smem + S;       // 2*S floats: scan levels; lv[0..S) ends as csum
  float* rwArr = smem + 2 * S;   // S floats
  int*   pad   = (int*)(smem + 3 * S); // S ints: round(csum)
  float* red   = smem + 4 * S;   // 64 floats
  int*   aa    = (int*)(smem + 4 * S + 64); // T+1 ints: firing frame per bin
  __shared__ int s_alen, s_m;

  const int b = blockIdx.x, tid = threadIdx.x, nt = blockDim.x;
  const float* iwr = iw + (size_t)b * S;
  const unsigned char* mr = mask + (size_t)b * S;
  const int tl = tlen[b];

  if (tid == 0) { s_alen = 0; s_m = 0; }
  __syncthreads();

  // 1. clip + mask, audio_len
  int myal = 0;
  for (int s = tid; s < S; s += nt) {
    float v = iwr[s];
    v = fminf(fmaxf(v, 0.0f), 1.0f);
    if (mr[s]) v = 0.0f; else myal++;
    w[s] = v;
  }
  atomicAdd(&s_alen, myal);
  __syncthreads();

  // 2. w_sum — 16 strided lanes + halving tree, all within wave 0
  if (tid < 16) {
    float acc = 0.0f;
    for (int i = tid; i < S; i += 16) acc += w[i];
    red[tid] = acc;
  }
  __builtin_amdgcn_wave_barrier();
  if (tid < 8) red[tid] = red[tid] + red[tid + 8];
  __builtin_amdgcn_wave_barrier();
  if (tid < 4) red[tid] = red[tid] + red[tid + 4];
  __builtin_amdgcn_wave_barrier();
  if (tid < 2) red[tid] = red[tid] + red[tid + 2];
  __builtin_amdgcn_wave_barrier();
  if (tid == 0) red[0] = red[0] + red[1];
  __syncthreads();
  const float wsum = red[0];
  if (tid == 0) o_wsum[b] = wsum;

  // 3. scale, seed scan level 0, init firing table
  const float desired = FT * (float)tl + 1e-4f;
  const float scale = desired / wsum;
  for (int s = tid; s < S; s += nt) { float sv = w[s] * scale; w[s] = sv; lv[s] = sv; }
  for (int i = tid; i <= T; i += nt) aa[i] = (i == 0) ? -1 : S;
  __syncthreads();

  int K = 0; while ((1 << K) < S) K++;   // S = 2^K

  // 4. up-sweep: level of size sz at offset 2S - 2*sz
  {
    int offp = 0, off = S, sz = S >> 1;
    while (sz >= 64) {
      for (int i = tid; i < sz; i += nt)
        lv[off + i] = lv[offp + 2 * i] + lv[offp + 2 * i + 1];
      __syncthreads();
      offp = off; off += sz; sz >>= 1;
    }
    // small levels: wave 0 only (sz = 32..1)
    if (tid < 64) {
      while (sz >= 1) {
        if (tid < sz)
          lv[off + tid] = lv[offp + 2 * tid] + lv[offp + 2 * tid + 1];
        __builtin_amdgcn_wave_barrier();
        offp = off; off += sz; sz >>= 1;
      }
      // 5a. down-sweep small levels: szk = 2..64 (k = K-1 .. K-6)
      for (int k = K - 1; k >= K - 6; --k) {
        int szk = S >> k;
        int ok  = 2 * S - 2 * szk;
        int ok1 = 2 * S - szk;
        if (tid > 0 && tid < szk) {
          if (tid & 1) lv[ok + tid] = lv[ok1 + (tid >> 1)];
          else         lv[ok + tid] = lv[ok1 + (tid >> 1) - 1] + lv[ok + tid];
        }
        __builtin_amdgcn_wave_barrier();
      }
    }
    __syncthreads();
    // 5b. down-sweep large levels: szk = 128..S
    for (int k = K - 7; k >= 0; --k) {
      int szk = S >> k;
      int ok  = 2 * S - 2 * szk;
      int ok1 = 2 * S - szk;
      for (int j = tid; j < szk; j += nt) {
        if (j == 0) continue;
        if (j & 1) lv[ok + j] = lv[ok1 + (j >> 1)];
        else       lv[ok + j] = lv[ok1 + (j >> 1) - 1] + lv[ok + j];
      }
      __syncthreads();
    }
  }

  // 6. per-frame quantities (lv[0..S) = csum)
  for (int s = tid; s < S; s += nt) {
    float c = lv[s];
    int ri = (int)floorf(c / FT); ri = min(max(ri, 0), T);
    int li = 0;
    if (s > 0) { int rp = (int)floorf(lv[s - 1] / FT); li = min(max(rp, 0), T); }
    int n = ri - li;
    int ex = max(n - 1, 0);
    float rw = (n > 0) ? (c - (float)ri * FT) : 0.0f;
    float lwv = (w[s] - rw) - (float)ex * FT;
    o_rw[(size_t)b * S + s] = rw;
    o_lw[(size_t)b * S + s] = lwv;
    rwArr[s] = rw;
    pad[s] = (int)rintf(c);
    if (n > 0) aa[ri] = s;  // unique per bin (n_fir <= 1)
  }
  __syncthreads();

  // 7. m = number of adjacent changes in capped seq
  {
    int my = 0;
    for (int j = tid; j < S; j += nt)
      my += (seqv_at(pad, S, tl, j) != seqv_at(pad, S, tl, j + 1));
    atomicAdd(&s_m, my);
  }
  __syncthreads();
  const int m = s_m;
  const int alen = s_alen;
  const int seq0 = seqv_at(pad, S, tl, 0);
  const int L = (m >= tl) ? m : m + 1;

  // 8. delay per bin: right contribution first, then ascending lefts
  for (int t = tid; t < T; t += nt) {
    int start = aa[t], end = aa[t + 1];
    int s0 = (start < 0) ? 0 : start;
    int s1 = min(end, S - 1);
    float d = 0.0f;
    for (int s = s0; s <= s1; ++s) {
      float cf = (s == start) ? rwArr[s] : (w[s] - rwArr[s]);
      d = d + (cf * (float)(s + 1)) / FT;
    }
    o_delay[(size_t)b * T + t] = d;
  }

  // 9. dur per bin via binary search on monotone pad
  for (int t = tid; t < T; t += nt) {
    int dv = 0;
    if (t < m) {
      int v = seq0 + t;
      dv = upper_b(pad, S, tl, v) - lower_b(pad, S, tl, v);
    }
    if (t == L - 1) dv += alen - lower_b(pad, S, tl, tl);
    o_dur[(size_t)b * T + t] = (float)dv;
  }
}

// Gather, 4 bins per block: interior boundary frames re-read from L1/L2
// (same CU) instead of a second HBM fetch from a different XCD.
#define KBINS 4
__global__ __launch_bounds__(128) void cif_gather_kernel(const float* __restrict__ in,
    const float* __restrict__ rw, const float* __restrict__ lw,
    const int* __restrict__ a_ws, float* __restrict__ out,
    int S, int T, int C)
{
  const int b = blockIdx.y;
  const int t0 = blockIdx.x * KBINS;
  const int* ab = a_ws + (size_t)b * (T + 1);
  const size_t bS = (size_t)b * S;
  const int c4 = threadIdx.x * 4;

  int bound[KBINS + 1];
#pragma unroll
  for (int k = 0; k <= KBINS; ++k) bound[k] = ab[min(t0 + k, T)];

#pragma unroll
  for (int k = 0; k < KBINS; ++k) {
    const int t = t0 + k;
    if (t >= T) break;
    const int st = bound[k];
    const int en = min(bound[k + 1], S - 1);
    float4 acc = make_float4(0.f, 0.f, 0.f, 0.f);
    for (int s = (st < 0 ? 0 : st); s <= en; ++s) {
      const float coeff = (s == st) ? rw[bS + s] : lw[bS + s];
      const float4 v = *reinterpret_cast<const float4*>(in + (bS + s) * (size_t)C + c4);
      acc.x += coeff * v.x; acc.y += coeff * v.y;
      acc.z += coeff * v.z; acc.w += coeff * v.w;
    }
    *reinterpret_cast<float4*>(out + ((size_t)b * T + t) * (size_t)C + c4) = acc;
  }
}

extern "C" void kernel_launch(void* const* d_in, const int* in_sizes, int n_in,
                              void* d_out, int out_size, void* d_ws, size_t ws_size,
                              hipStream_t stream)
{
  const float* inp = (const float*)d_in[0];
  const float* iw  = (const float*)d_in[1];
  const unsigned char* mask = (const unsigned char*)d_in[2];
  const int* tl = (const int*)d_in[3];
  const int B = in_sizes[3];
  const int S = in_sizes[1] / B;
  const int C = in_sizes[0] / in_sizes[1];
  const long long T = ((long long)out_size - B - 2LL * B * S) / ((long long)B * C + 2LL * B);

  float* o = (float*)d_out;
  float* o_out   = o;
  float* o_delay = o_out + (size_t)B * T * C;
  float* o_dur   = o_delay + (size_t)B * T;
  float* o_wsum  = o_dur + (size_t)B * T;
  float* o_rw    = o_wsum + B;
  float* o_lw    = o_rw + (size_t)B * S;
  int* a_ws = (int*)d_ws;  // B*(T+1) ints

  size_t smem = (size_t)(4 * S + 64) * sizeof(float) + (size_t)(T + 1) * sizeof(int);
  hipLaunchKernelGGL(cif_row_kernel, dim3(B), dim3(512), smem, stream,
                     iw, mask, tl, o_wsum, o_rw, o_lw, o_delay, o_dur, a_ws, S, (int)T);
  dim3 g2((unsigned)((T + KBINS - 1) / KBINS), (unsigned)B);
  hipLaunchKernelGGL(cif_gather_kernel, g2, dim3(C / 4), 0, stream,
                     inp, o_rw, o_lw, a_ws, o_out, S, (int)T, C);
}

// Round 4
// 32.248 us; speedup vs baseline: 1.1086x; 1.0143x over previous
//
#include <hip/hip_runtime.h>

#define FT 1.0f

typedef float fvec4 __attribute__((ext_vector_type(4)));

__device__ __forceinline__ int seqv_at(const int* pad, int S, int tl, int j) {
  return (j < S) ? min(pad[j], tl) : tl;
}

__device__ __forceinline__ int lower_b(const int* pad, int S, int tl, int v) {
  int lo = 0, hi = S + 1;
  while (lo < hi) { int mid = (lo + hi) >> 1; if (seqv_at(pad, S, tl, mid) >= v) hi = mid; else lo = mid + 1; }
  return lo;
}
__device__ __forceinline__ int upper_b(const int* pad, int S, int tl, int v) {
  int lo = 0, hi = S + 1;
  while (lo < hi) { int mid = (lo + hi) >> 1; if (seqv_at(pad, S, tl, mid) > v) hi = mid; else lo = mid + 1; }
  return lo;
}

// One block per batch row. Bit-exact vs jax-CPU (verified rounds 1-2):
//  - w_sum: 16 strided lanes + halving tree (XLA:CPU vectorized reduce)
//  - cumsum: lax.associative_scan recursive decomposition
// Round 4: round-3 plan with the nontemporal-store type fixed (native clang
// vector, not HIP_vector_type).
__global__ __launch_bounds__(512) void cif_row_kernel(
    const float* __restrict__ iw, const unsigned char* __restrict__ mask,
    const int* __restrict__ tlen,
    float* __restrict__ o_wsum, float* __restrict__ o_rw, float* __restrict__ o_lw,
    float* __restrict__ o_delay, float* __restrict__ o_dur,
    int* __restrict__ a_ws, int S, int T)
{
  extern __shared__ float smem[];
  float* w     = smem;           // S floats (clipped, later scaled w)
  float* lv    = smem + S;       // 2*S floats: scan levels; lv[0..S) ends as csum
  float* rwArr = smem + 2 * S;   // S floats
  int*   pad   = (int*)(smem + 3 * S); // S ints: round(csum)
  float* red   = smem + 4 * S;   // 64 floats
  int*   aa    = (int*)(smem + 4 * S + 64); // T+1 ints: firing frame per bin
  __shared__ int s_alen, s_m;

  const int b = blockIdx.x, tid = threadIdx.x, nt = blockDim.x;
  const float* iwr = iw + (size_t)b * S;
  const unsigned char* mr = mask + (size_t)b * S;
  const int tl = tlen[b];

  if (tid == 0) { s_alen = 0; s_m = 0; }

  // 1. clip + mask, audio_len
  int myal = 0;
  for (int s = tid; s < S; s += nt) {
    float v = iwr[s];
    v = fminf(fmaxf(v, 0.0f), 1.0f);
    if (mr[s]) v = 0.0f; else myal++;
    w[s] = v;
  }
  __syncthreads();                 // B1: w[] + s_alen/s_m init visible
  atomicAdd(&s_alen, myal);        // consumed only after later barriers

  // 2. wave 0: w_sum (16 strided lanes + halving tree); waves 1-7: aa init
  if (tid < 64) {
    if (tid < 16) {
      float acc = 0.0f;
      for (int i = tid; i < S; i += 16) acc += w[i];
      red[tid] = acc;
    }
    __builtin_amdgcn_wave_barrier();
    if (tid < 8) red[tid] = red[tid] + red[tid + 8];
    __builtin_amdgcn_wave_barrier();
    if (tid < 4) red[tid] = red[tid] + red[tid + 4];
    __builtin_amdgcn_wave_barrier();
    if (tid < 2) red[tid] = red[tid] + red[tid + 2];
    __builtin_amdgcn_wave_barrier();
    if (tid == 0) red[0] = red[0] + red[1];
  } else {
    for (int i = tid - 64; i <= T; i += nt - 64) aa[i] = (i == 0) ? -1 : S;
  }
  __syncthreads();                 // B2
  const float wsum = red[0];
  if (tid == 0) o_wsum[b] = wsum;

  // 3. scale, seed scan level 0
  const float desired = FT * (float)tl + 1e-4f;
  const float scale = desired / wsum;
  for (int s = tid; s < S; s += nt) { float sv = w[s] * scale; w[s] = sv; lv[s] = sv; }
  __syncthreads();                 // B3

  int K = 0; while ((1 << K) < S) K++;   // S = 2^K (2048 -> K=11)

  // 4. up-sweep, level of size sz at offset 2S - 2*sz; multi-wave while sz>=128
  {
    int offp = 0, off = S, sz = S >> 1;
    while (sz >= 128) {
      for (int i = tid; i < sz; i += nt)
        lv[off + i] = lv[offp + 2 * i] + lv[offp + 2 * i + 1];
      __syncthreads();             // B4..B7
      offp = off; off += sz; sz >>= 1;
    }
    // wave 0 only: up-sweep sz=64..1, then down-sweep szk=2..128
    if (tid < 64) {
      while (sz >= 1) {
        for (int i = tid; i < sz; i += 64)
          lv[off + i] = lv[offp + 2 * i] + lv[offp + 2 * i + 1];
        __builtin_amdgcn_wave_barrier();
        offp = off; off += sz; sz >>= 1;
      }
      for (int k = K - 1; k >= K - 7; --k) {   // szk = 2,4,...,128
        int szk = S >> k;
        int ok  = 2 * S - 2 * szk;
        int ok1 = 2 * S - szk;
        for (int j = tid; j < szk; j += 64) {
          if (j == 0) continue;
          if (j & 1) lv[ok + j] = lv[ok1 + (j >> 1)];
          else       lv[ok + j] = lv[ok1 + (j >> 1) - 1] + lv[ok + j];
        }
        __builtin_amdgcn_wave_barrier();
      }
    }
    __syncthreads();               // B8
    // 5. down-sweep large levels: szk = 256..S
    for (int k = K - 8; k >= 0; --k) {
      int szk = S >> k;
      int ok  = 2 * S - 2 * szk;
      int ok1 = 2 * S - szk;
      for (int j = tid; j < szk; j += nt) {
        if (j == 0) continue;
        if (j & 1) lv[ok + j] = lv[ok1 + (j >> 1)];
        else       lv[ok + j] = lv[ok1 + (j >> 1) - 1] + lv[ok + j];
      }
      __syncthreads();             // B9..B12
    }
  }

  // 6. per-frame quantities (lv[0..S) = csum)
  for (int s = tid; s < S; s += nt) {
    float c = lv[s];
    int ri = (int)floorf(c / FT); ri = min(max(ri, 0), T);
    int li = 0;
    if (s > 0) { int rp = (int)floorf(lv[s - 1] / FT); li = min(max(rp, 0), T); }
    int n = ri - li;
    int ex = max(n - 1, 0);
    float rw = (n > 0) ? (c - (float)ri * FT) : 0.0f;
    float lwv = (w[s] - rw) - (float)ex * FT;
    o_rw[(size_t)b * S + s] = rw;
    o_lw[(size_t)b * S + s] = lwv;
    rwArr[s] = rw;
    pad[s] = (int)rintf(c);
    if (n > 0) aa[ri] = s;  // unique per bin (n_fir <= 1)
  }
  __syncthreads();                 // B13

  // 7. m count (atomic latency overlapped with phase 8)
  {
    int my = 0;
    for (int j = tid; j < S; j += nt)
      my += (seqv_at(pad, S, tl, j) != seqv_at(pad, S, tl, j + 1));
    atomicAdd(&s_m, my);
  }

  // 8. delay per bin: right contribution first, then ascending lefts
  for (int t = tid; t < T; t += nt) {
    int start = aa[t], end = aa[t + 1];
    int s0 = (start < 0) ? 0 : start;
    int s1 = min(end, S - 1);
    float d = 0.0f;
    for (int s = s0; s <= s1; ++s) {
      float cf = (s == start) ? rwArr[s] : (w[s] - rwArr[s]);
      d = d + (cf * (float)(s + 1)) / FT;
    }
    __builtin_nontemporal_store(d, &o_delay[(size_t)b * T + t]);
  }
  __syncthreads();                 // B14 (s_m ready)

  const int m = s_m;
  const int alen = s_alen;
  const int seq0 = seqv_at(pad, S, tl, 0);
  const int L = (m >= tl) ? m : m + 1;

  // 9. dur per bin via binary search on monotone pad
  for (int t = tid; t < T; t += nt) {
    int dv = 0;
    if (t < m) {
      int v = seq0 + t;
      dv = upper_b(pad, S, tl, v) - lower_b(pad, S, tl, v);
    }
    if (t == L - 1) dv += alen - lower_b(pad, S, tl, tl);
    __builtin_nontemporal_store((float)dv, &o_dur[(size_t)b * T + t]);
  }
}

// Gather, KBINS bins per block: boundary frames shared between consecutive
// bins of the same block hit L1/L2 instead of a second HBM fetch.
#define KBINS 8
__global__ __launch_bounds__(128) void cif_gather_kernel(const float* __restrict__ in,
    const float* __restrict__ rw, const float* __restrict__ lw,
    const int* __restrict__ a_ws, float* __restrict__ out,
    int S, int T, int C)
{
  const int b = blockIdx.y;
  const int t0 = blockIdx.x * KBINS;
  const int* ab = a_ws + (size_t)b * (T + 1);
  const size_t bS = (size_t)b * S;
  const int c4 = threadIdx.x * 4;

  int bound[KBINS + 1];
#pragma unroll
  for (int k = 0; k <= KBINS; ++k) bound[k] = ab[min(t0 + k, T)];

#pragma unroll
  for (int k = 0; k < KBINS; ++k) {
    const int t = t0 + k;
    if (t >= T) break;
    const int st = bound[k];
    const int en = min(bound[k + 1], S - 1);
    fvec4 acc = (fvec4)0.0f;
    for (int s = (st < 0 ? 0 : st); s <= en; ++s) {
      const float coeff = (s == st) ? rw[bS + s] : lw[bS + s];
      const fvec4 v = *reinterpret_cast<const fvec4*>(in + (bS + s) * (size_t)C + c4);
      acc += coeff * v;
    }
    __builtin_nontemporal_store(acc,
        reinterpret_cast<fvec4*>(out + ((size_t)b * T + t) * (size_t)C + c4));
  }
}

extern "C" void kernel_launch(void* const* d_in, const int* in_sizes, int n_in,
                              void* d_out, int out_size, void* d_ws, size_t ws_size,
                              hipStream_t stream)
{
  const float* inp = (const float*)d_in[0];
  const float* iw  = (const float*)d_in[1];
  const unsigned char* mask = (const unsigned char*)d_in[2];
  const int* tl = (const int*)d_in[3];
  const int B = in_sizes[3];
  const int S = in_sizes[1] / B;
  const int C = in_sizes[0] / in_sizes[1];
  const long long T = ((long long)out_size - B - 2LL * B * S) / ((long long)B * C + 2LL * B);

  float* o = (float*)d_out;
  float* o_out   = o;
  float* o_delay = o_out + (size_t)B * T * C;
  float* o_dur   = o_delay + (size_t)B * T;
  float* o_wsum  = o_dur + (size_t)B * T;
  float* o_rw    = o_wsum + B;
  float* o_lw    = o_rw + (size_t)B * S;
  int* a_ws = (int*)d_ws;  // B*(T+1) ints

  size_t smem = (size_t)(4 * S + 64) * sizeof(float) + (size_t)(T + 1) * sizeof(int);
  hipLaunchKernelGGL(cif_row_kernel, dim3(B), dim3(512), smem, stream,
                     iw, mask, tl, o_wsum, o_rw, o_lw, o_delay, o_dur, a_ws, S, (int)T);
  dim3 g2((unsigned)((T + KBINS - 1) / KBINS), (unsigned)B);
  hipLaunchKernelGGL(cif_gather_kernel, g2, dim3(C / 4), 0, stream,
                     inp, o_rw, o_lw, a_ws, o_out, S, (int)T, C);
}